// Round 1
// baseline (594.397 us; speedup 1.0000x reference)
//
#include <hip/hip_runtime.h>

// GAT encoder: N=50000 nodes, E=800000 edges, H=4 heads, C=64 dims.
//
// R4: drop the counting-sort/CSR pipeline entirely. R3's factorization means
// each edge only contributes 12 scalars per dst node (D,Sx,Sy per head), so a
// direct fire-and-forget global_atomic_add_f32 scatter (9.6M RMWs over 600K
// addresses, ~16/address) replaces hist+scan1/2/3+scatter (5 dependent
// dispatches + ~30MB traffic). Pipeline: memset(acc) -> precompute ->
// edge_kernel (atomic scatter-add) -> node_kernel (self-loop + epilogue).
// 4 dispatches instead of 9.
//
// History: R1 same-address float atomicAdd of full messages = 170us -> sort.
// R2 single-block scan 126us -> 3-phase scan. R3 factored (D,Sx,Sy) per head.

#define N_NODES 50000
#define N_EDGES 800000
#define EDGE_BLOCKS (N_EDGES / 256)     // 3125, exact
#define NODE_BLOCKS (N_NODES / 4)       // 12500, exact (4 nodes x 64 thr)

// ---- workspace layout (bytes) ----
// scal float[32]: [0..7]=ws(h,k) [8..15]=wd(h,k) [16..19]=we(h)
constexpr size_t OFF_SCAL  = 0;
constexpr size_t OFF_EASUM = 128;     // float[64] bucketed ea partial sums
constexpr size_t OFF_ACC   = 512;     // float[N*16]: per node D[4],Sx[4],Sy[4],pad[4]
constexpr size_t ACC_BYTES = (size_t)N_NODES * 16 * sizeof(float);

__global__ void precompute_kernel(const float* __restrict__ W,
                                  const float* __restrict__ att_src,
                                  const float* __restrict__ att_dst,
                                  const float* __restrict__ W_edge,
                                  const float* __restrict__ att_edge,
                                  float* __restrict__ scal) {
    int t = threadIdx.x;            // 0..255 = (h*64 + c)
    int h = t >> 6, lane = t & 63;
    float w0 = W[2 * t], w1 = W[2 * t + 1];
    float as = att_src[t], ad = att_dst[t];
    float ae = att_edge[t], wE = W_edge[t];
    float v0 = as * w0, v1 = as * w1, v2 = ad * w0, v3 = ad * w1, v4 = ae * wE;
    for (int off = 32; off; off >>= 1) {
        v0 += __shfl_down(v0, off, 64);
        v1 += __shfl_down(v1, off, 64);
        v2 += __shfl_down(v2, off, 64);
        v3 += __shfl_down(v3, off, 64);
        v4 += __shfl_down(v4, off, 64);
    }
    if (lane == 0) {
        scal[2 * h]     = v0;  scal[2 * h + 1] = v1;
        scal[8 + 2 * h] = v2;  scal[9 + 2 * h] = v3;
        scal[16 + h]    = v4;
    }
}

// One thread per edge. Compute per-head unnormalized exp(alpha) and
// scatter-add (D, Sx, Sy) to the dst node's accumulator with f32 atomics.
// Atomics are fire-and-forget (result unused -> no wait). Also reduce
// sum(ea) into 64 buckets for the self-loop mean.
__global__ __launch_bounds__(256) void edge_kernel(
        const int* __restrict__ ei, const float* __restrict__ ea,
        const float2* __restrict__ x2, const float* __restrict__ scal,
        float* __restrict__ acc, float* __restrict__ easum) {
    __shared__ float sm[4];
    int e = blockIdx.x * 256 + threadIdx.x;

    float ws0[4], ws1[4], wd0[4], wd1[4], we[4];
#pragma unroll
    for (int h = 0; h < 4; ++h) {
        ws0[h] = scal[2 * h];     ws1[h] = scal[2 * h + 1];
        wd0[h] = scal[8 + 2 * h]; wd1[h] = scal[9 + 2 * h];
        we[h]  = scal[16 + h];
    }

    int src = ei[e], dst = ei[N_EDGES + e];
    float2 xs = x2[src];
    float2 xd = x2[dst];
    float eav = ea[e];

    float* a = acc + (size_t)dst * 16;
#pragma unroll
    for (int h = 0; h < 4; ++h) {
        float al = xs.x * ws0[h] + xs.y * ws1[h]
                 + xd.x * wd0[h] + xd.y * wd1[h] + eav * we[h];
        al = fmaxf(al, 0.2f * al);
        float ex = __expf(al);
        atomicAdd(a + h,     ex);
        atomicAdd(a + 4 + h, ex * xs.x);
        atomicAdd(a + 8 + h, ex * xs.y);
    }

    // block-reduce ea, 64-way bucketed to avoid same-address serialization
    float v = eav;
    for (int off = 32; off; off >>= 1) v += __shfl_down(v, off, 64);
    if ((threadIdx.x & 63) == 0) sm[threadIdx.x >> 6] = v;
    __syncthreads();
    if (threadIdx.x == 0)
        atomicAdd(&easum[blockIdx.x & 63], sm[0] + sm[1] + sm[2] + sm[3]);
}

// 64 threads per node (4 nodes per block). Thread j in [0,64) owns output
// float4 j (channels 4j..4j+3, head j>>4): add the self-loop contribution,
// then out = (W . [Sx,Sy]) / D + bias. Fully coalesced 51.2MB write.
__global__ __launch_bounds__(256) void node_kernel(
        const float2* __restrict__ x2, const float4* __restrict__ W4,
        const float* __restrict__ scal, const float* __restrict__ acc,
        const float* __restrict__ easum, const float4* __restrict__ bias4,
        float4* __restrict__ out4) {
    int t = threadIdx.x;
    int node = blockIdx.x * 4 + (t >> 6);
    int j = t & 63;
    int h = j >> 4;

    float es = 0.0f;
#pragma unroll
    for (int i = 0; i < 64; ++i) es += easum[i];   // uniform -> scalar loads
    float meanea = es * (1.0f / N_EDGES);

    float ws0 = scal[2 * h],     ws1 = scal[2 * h + 1];
    float wd0 = scal[8 + 2 * h], wd1 = scal[9 + 2 * h];
    float we  = scal[16 + h];

    float2 xd = x2[node];

    // self loop: src = dst, ea = mean(ea)
    float al = xd.x * (ws0 + wd0) + xd.y * (ws1 + wd1) + meanea * we;
    al = fmaxf(al, 0.2f * al);
    float ex = __expf(al);

    const float* a = acc + (size_t)node * 16;
    float D  = a[h]     + ex;
    float Sx = a[4 + h] + ex * xd.x;
    float Sy = a[8 + h] + ex * xd.y;
    float invD = 1.0f / D;

    float4 wa = W4[2 * j], wb = W4[2 * j + 1], b = bias4[j];
    float4 o;
    o.x = (wa.x * Sx + wa.y * Sy) * invD + b.x;
    o.y = (wa.z * Sx + wa.w * Sy) * invD + b.y;
    o.z = (wb.x * Sx + wb.y * Sy) * invD + b.z;
    o.w = (wb.z * Sx + wb.w * Sy) * invD + b.w;
    out4[(size_t)node * 64 + j] = o;
}

extern "C" void kernel_launch(void* const* d_in, const int* in_sizes, int n_in,
                              void* d_out, int out_size, void* d_ws, size_t ws_size,
                              hipStream_t stream) {
    const float* x        = (const float*)d_in[0];
    const int*   ei       = (const int*)  d_in[1];
    const float* ea       = (const float*)d_in[2];
    const float* W        = (const float*)d_in[3];
    const float* att_src  = (const float*)d_in[4];
    const float* att_dst  = (const float*)d_in[5];
    const float* W_edge   = (const float*)d_in[6];
    const float* att_edge = (const float*)d_in[7];
    const float* bias     = (const float*)d_in[8];

    char* ws = (char*)d_ws;
    float* scal  = (float*)(ws + OFF_SCAL);
    float* easum = (float*)(ws + OFF_EASUM);
    float* acc   = (float*)(ws + OFF_ACC);

    // zero scal+easum+acc in one fill (precompute rewrites scal afterwards)
    hipMemsetAsync(ws, 0, OFF_ACC + ACC_BYTES, stream);
    precompute_kernel<<<1, 256, 0, stream>>>(W, att_src, att_dst, W_edge, att_edge, scal);
    edge_kernel<<<EDGE_BLOCKS, 256, 0, stream>>>(ei, ea, (const float2*)x, scal, acc, easum);
    node_kernel<<<NODE_BLOCKS, 256, 0, stream>>>(
        (const float2*)x, (const float4*)W, scal, acc, easum,
        (const float4*)bias, (float4*)d_out);
}